// Round 4
// baseline (195.392 us; speedup 1.0000x reference)
//
#include <hip/hip_runtime.h>
#include <math.h>

// Problem constants
#define B_TOT 256
#define N_N   8
#define P_P   1152
#define J_J   160        // L*O
#define K_K   9216       // N_N * P_P
#define L_L   10

// GEMM config
#define SG    18                 // split-K super-slices (512 k per block)
#define JG    5                  // j-groups of 32
#define BLOCKS_PER_BT (SG * JG)  // 90 blocks feed each 16-batch strip

typedef __attribute__((ext_vector_type(8))) short short8;   // 8 x bf16
typedef __attribute__((ext_vector_type(4))) float f32x4;

__device__ __forceinline__ short f2bf(float f) {
    unsigned u = __builtin_bit_cast(unsigned, f);
    unsigned r = (u + 0x7fffu + ((u >> 16) & 1u)) >> 16;   // RNE
    return (short)r;
}

// ---------------------------------------------------------------------------
// Kernel 1: W (1,P,L,O,N) fp32 -> Bt[j][k] bf16, j = l*16+o, k = n*1152+p.
// Also zeroes the fan-in counters (must happen every launch: graph replays).
// ---------------------------------------------------------------------------
__global__ __launch_bounds__(256) void transform_w(const float* __restrict__ W,
                                                   short* __restrict__ Bt,
                                                   int* __restrict__ ctr) {
    const int p0 = blockIdx.x * 128;
    const int j0 = blockIdx.y * 4;
    const int tid = threadIdx.x;
    if (blockIdx.x == 0 && blockIdx.y == 0 && tid < 16) ctr[tid] = 0;

    __shared__ float lds[128][33];   // +1 pad

    #pragma unroll
    for (int it = 0; it < 16; ++it) {
        const int idx = it * 256 + tid;
        const int p = idx >> 5;
        const int f = idx & 31;
        lds[p][f] = W[(size_t)(p0 + p) * 1280 + j0 * 8 + f];
    }
    __syncthreads();
    #pragma unroll
    for (int it = 0; it < 16; ++it) {
        const int idx = it * 256 + tid;
        const int c  = idx >> 7;    // 0..31 = dj*8 + n
        const int pp = idx & 127;
        const int dj = c >> 3;
        const int n  = c & 7;
        Bt[(size_t)(j0 + dj) * K_K + n * P_P + p0 + pp] = f2bf(lds[pp][c]);
    }
}

// ---------------------------------------------------------------------------
// Kernel 2: split-K MFMA GEMM + fan-in reduce + squash (stream-K style).
// grid = (16 bt, 18 sg, 5 jg), 256 threads = 4 waves.
// Wave w: 16 b x 32 j x 128 k (4 k-steps, 2 MFMA chains).
// Block: LDS-reduce the 4 waves -> one partial write part[b][sg][j].
// Last block per bt (atomic fan-in) reduces 18 slices + squash -> d_out.
// ---------------------------------------------------------------------------
__global__ __launch_bounds__(256) void gemm_fused(const float* __restrict__ x,
                                                  const short* __restrict__ Bt,
                                                  float* __restrict__ part,
                                                  int* __restrict__ ctr,
                                                  float* __restrict__ out) {
    const int bt = blockIdx.x;      // 0..15
    const int sg = blockIdx.y;      // 0..17
    const int jg = blockIdx.z;      // 0..4
    const int tid  = threadIdx.x;
    const int w    = tid >> 6;      // wave 0..3
    const int lane = tid & 63;
    const int m  = lane & 15;
    const int kq = lane >> 4;       // 0..3
    const int b0 = bt * 16;
    const int k0 = sg * 512 + w * 128;

    const float* xrow  = x  + (size_t)(b0 + m) * K_K + k0 + kq * 8;
    const short* brow0 = Bt + (size_t)(jg * 32 + m) * K_K + k0 + kq * 8;
    const short* brow1 = brow0 + (size_t)16 * K_K;

    f32x4 acc0 = {0.f, 0.f, 0.f, 0.f};
    f32x4 acc1 = {0.f, 0.f, 0.f, 0.f};

    #pragma unroll
    for (int ks = 0; ks < 4; ++ks) {
        const f32x4 a0 = *reinterpret_cast<const f32x4*>(xrow + ks * 32);
        const f32x4 a1 = *reinterpret_cast<const f32x4*>(xrow + ks * 32 + 4);
        short8 af;
        af[0] = f2bf(a0.x); af[1] = f2bf(a0.y); af[2] = f2bf(a0.z); af[3] = f2bf(a0.w);
        af[4] = f2bf(a1.x); af[5] = f2bf(a1.y); af[6] = f2bf(a1.z); af[7] = f2bf(a1.w);
        const short8 bf0 = *reinterpret_cast<const short8*>(brow0 + ks * 32);
        const short8 bf1 = *reinterpret_cast<const short8*>(brow1 + ks * 32);
        acc0 = __builtin_amdgcn_mfma_f32_16x16x32_bf16(af, bf0, acc0, 0, 0, 0);
        acc1 = __builtin_amdgcn_mfma_f32_16x16x32_bf16(af, bf1, acc1, 0, 0, 0);
    }

    // ---- cross-wave split-K reduce in LDS ----
    __shared__ float redux[4][64][8];   // 8 KB
    #pragma unroll
    for (int r = 0; r < 4; ++r) {
        redux[w][lane][r]     = acc0[r];
        redux[w][lane][r + 4] = acc1[r];
    }
    __syncthreads();

    // 512 block outputs; each thread writes 2. Deterministic order w=0..3.
    #pragma unroll
    for (int f = tid; f < 512; f += 256) {
        const int ln = f >> 3;
        const int c  = f & 7;
        const float s = redux[0][ln][c] + redux[1][ln][c]
                      + redux[2][ln][c] + redux[3][ln][c];
        const int mm = ln & 15;
        const int kk = ln >> 4;
        const int ch = c >> 2;
        const int r  = c & 3;
        const int b  = b0 + kk * 4 + r;
        const int j  = jg * 32 + ch * 16 + mm;
        part[((size_t)b * SG + sg) * J_J + j] = s;
    }

    // ---- fan-in: last block of this bt reduces + squashes ----
    __threadfence();            // release this thread's part stores (agent scope)
    __syncthreads();            // all threads' fences precede the atomic
    __shared__ int isLast;
    if (tid == 0) {
        const int prev = __hip_atomic_fetch_add(&ctr[bt], 1, __ATOMIC_ACQ_REL,
                                                __HIP_MEMORY_SCOPE_AGENT);
        isLast = (prev == BLOCKS_PER_BT - 1);
    }
    __syncthreads();
    if (!isLast) return;

    __shared__ float sld[16][J_J];   // 10 KB
    __shared__ float msq[256];       // [b][o]

    for (int idx = tid; idx < 16 * J_J; idx += 256) {
        const int b = idx / J_J;
        const int j = idx - b * J_J;
        const float* pb = part + ((size_t)(b0 + b) * SG) * J_J + j;
        float s = 0.f;
        #pragma unroll 6
        for (int si = 0; si < SG; ++si) s += pb[(size_t)si * J_J];
        sld[b][j] = s;
    }
    __syncthreads();

    {
        const int b = tid >> 4;
        const int o = tid & 15;
        float ms = 0.f;
        #pragma unroll
        for (int l = 0; l < L_L; ++l) {
            const float v = sld[b][l * 16 + o];
            ms = fmaf(v, v, ms);
        }
        msq[tid] = ms;
    }
    __syncthreads();

    for (int idx = tid; idx < 16 * J_J; idx += 256) {
        const int b = idx / J_J;
        const int j = idx - b * J_J;
        const float s  = sld[b][j];
        const float ms = msq[(b << 4) + (j & 15)];
        out[(size_t)(b0 + b) * J_J + j] = s * (sqrtf(ms) / (1.0f + ms));
    }
}

// ---------------------------------------------------------------------------
extern "C" void kernel_launch(void* const* d_in, const int* in_sizes, int n_in,
                              void* d_out, int out_size, void* d_ws, size_t ws_size,
                              hipStream_t stream) {
    const float* x = (const float*)d_in[0];   // (256, 8, 1152)
    const float* W = (const float*)d_in[1];   // (1, 1152, 10, 16, 8)
    float* out = (float*)d_out;               // (256, 10, 16)

    short* Bt   = (short*)d_ws;                                    // J*K bf16
    float* part = (float*)((char*)d_ws + (size_t)J_J * K_K * 2);   // B*SG*J fp32
    int*   ctr  = (int*)(part + (size_t)B_TOT * SG * J_J);         // 16 ints

    dim3 gt(P_P / 128, J_J / 4);
    transform_w<<<gt, 256, 0, stream>>>(W, Bt, ctr);

    dim3 gg(B_TOT / 16, SG, JG);
    gemm_fused<<<gg, 256, 0, stream>>>(x, Bt, part, ctr, out);
}

// Round 5
// 18.668 us; speedup vs baseline: 10.4668x; 10.4668x over previous
//
#include <hip/hip_runtime.h>
#include <math.h>

// Problem constants
#define B_TOT 256
#define N_N   8
#define P_P   1152
#define J_J   160        // L*O
#define K_K   9216       // N_N * P_P
#define L_L   10

// Split-K: slice sg owns k-subset {n*1152 + p : p in [64*sg, 64*sg+64), all n}
// Block-local k order: kk = dp*8 + n  (dp = p - 64*sg)
#define SG 18
#define JG 5

typedef __attribute__((ext_vector_type(8))) short short8;   // 8 x bf16
typedef __attribute__((ext_vector_type(4))) float f32x4;

__device__ __forceinline__ short f2bf(float f) {
    unsigned u = __builtin_bit_cast(unsigned, f);
    unsigned r = (u + 0x7fffu + ((u >> 16) & 1u)) >> 16;   // RNE
    return (short)r;
}

// ---------------------------------------------------------------------------
// Kernel 1: split-K MFMA GEMM reading x and W directly (no pre-transform).
// grid = (16 bt, 18 sg, 5 jg), 256 threads = 4 waves. NO device-scope fences.
// Stage: x-tile 16b x 512kk -> As bf16 (LDS transpose, padded rows).
// Compute: wave w owns kk in [w*128, w*128+128); B-frags straight from W:
//   kk = dp*8+n  ->  p = p0+dp,  B row j: W[p*1280 + j*8 + n], two float4.
// Block LDS-reduces 4 waves -> one partial write part[b][sg][j].
// ---------------------------------------------------------------------------
__global__ __launch_bounds__(256) void gemm_direct(const float* __restrict__ x,
                                                   const float* __restrict__ W,
                                                   float* __restrict__ part) {
    const int bt = blockIdx.x;      // 0..15
    const int sg = blockIdx.y;      // 0..17
    const int jg = blockIdx.z;      // 0..4
    const int tid  = threadIdx.x;
    const int w    = tid >> 6;      // wave 0..3
    const int lane = tid & 63;
    const int b0 = bt * 16;
    const int p0 = sg * 64;
    const int j0 = jg * 32;

    __shared__ short As[16][520];        // [b][kk], rows padded 512->520 (2-way only)
    __shared__ float redux[4][64][8];    // 8 KB cross-wave reduce

    // ---- stage x-tile: lane = dp, 8 coalesced dword loads per b-row ----
    {
        const float* xb = x + (size_t)b0 * K_K + p0 + lane;
        #pragma unroll
        for (int i = 0; i < 4; ++i) {
            const int bb = w * 4 + i;
            const float* xr = xb + (size_t)bb * K_K;
            short8 sh;
            #pragma unroll
            for (int n = 0; n < 8; ++n)
                sh[n] = f2bf(xr[(size_t)n * P_P]);
            *reinterpret_cast<short8*>(&As[bb][lane * 8]) = sh;  // kk = lane*8 + n
        }
    }
    __syncthreads();

    const int m  = lane & 15;
    const int kq = lane >> 4;       // 0..3

    f32x4 acc0 = {0.f, 0.f, 0.f, 0.f};
    f32x4 acc1 = {0.f, 0.f, 0.f, 0.f};

    // B base: p = p0 + w*16 + kq (+ ks*4), j = j0 + m (+16 for chain 1)
    const float* wbase = W + (size_t)(p0 + w * 16 + kq) * 1280 + (size_t)(j0 + m) * 8;

    #pragma unroll
    for (int ks = 0; ks < 4; ++ks) {
        const short8 af =
            *reinterpret_cast<const short8*>(&As[m][w * 128 + ks * 32 + kq * 8]);
        const float* wp0 = wbase + (size_t)ks * 4 * 1280;
        const float* wp1 = wp0 + 128;     // j += 16
        const f32x4 a0 = *reinterpret_cast<const f32x4*>(wp0);
        const f32x4 a1 = *reinterpret_cast<const f32x4*>(wp0 + 4);
        const f32x4 c0 = *reinterpret_cast<const f32x4*>(wp1);
        const f32x4 c1 = *reinterpret_cast<const f32x4*>(wp1 + 4);
        short8 bf0, bf1;
        bf0[0] = f2bf(a0.x); bf0[1] = f2bf(a0.y); bf0[2] = f2bf(a0.z); bf0[3] = f2bf(a0.w);
        bf0[4] = f2bf(a1.x); bf0[5] = f2bf(a1.y); bf0[6] = f2bf(a1.z); bf0[7] = f2bf(a1.w);
        bf1[0] = f2bf(c0.x); bf1[1] = f2bf(c0.y); bf1[2] = f2bf(c0.z); bf1[3] = f2bf(c0.w);
        bf1[4] = f2bf(c1.x); bf1[5] = f2bf(c1.y); bf1[6] = f2bf(c1.z); bf1[7] = f2bf(c1.w);
        acc0 = __builtin_amdgcn_mfma_f32_16x16x32_bf16(af, bf0, acc0, 0, 0, 0);
        acc1 = __builtin_amdgcn_mfma_f32_16x16x32_bf16(af, bf1, acc1, 0, 0, 0);
    }

    // ---- cross-wave split-K reduce in LDS (deterministic order) ----
    #pragma unroll
    for (int r = 0; r < 4; ++r) {
        redux[w][lane][r]     = acc0[r];
        redux[w][lane][r + 4] = acc1[r];
    }
    __syncthreads();

    #pragma unroll
    for (int f = tid; f < 512; f += 256) {
        const int ln = f >> 3;
        const int c  = f & 7;
        const float s = redux[0][ln][c] + redux[1][ln][c]
                      + redux[2][ln][c] + redux[3][ln][c];
        const int mm = ln & 15;
        const int kk = ln >> 4;
        const int ch = c >> 2;
        const int r  = c & 3;
        const int b  = b0 + kk * 4 + r;
        const int j  = j0 + ch * 16 + mm;
        part[((size_t)b * SG + sg) * J_J + j] = s;
    }
}

// ---------------------------------------------------------------------------
// Kernel 2: reduce partials over slices + squash (norm over L axis) -> out
// part[b][si][j]: per-b strip is SG*160 floats contiguous.
// ---------------------------------------------------------------------------
__global__ __launch_bounds__(192) void reduce_squash(const float* __restrict__ part,
                                                     float* __restrict__ out) {
    const int b = blockIdx.x;
    const int j = threadIdx.x;
    __shared__ float sld[J_J];
    float s = 0.0f;
    if (j < J_J) {
        const float* pb = part + (size_t)b * SG * J_J + j;
        #pragma unroll 6
        for (int si = 0; si < SG; ++si)
            s += pb[(size_t)si * J_J];
        sld[j] = s;
    }
    __syncthreads();
    if (j < J_J) {
        const int o = j & 15;
        float msq = 0.0f;
        #pragma unroll
        for (int l = 0; l < L_L; ++l) {
            const float v = sld[l * 16 + o];
            msq = fmaf(v, v, msq);
        }
        const float mag = sqrtf(msq);
        out[(size_t)b * J_J + j] = s * (mag / (1.0f + msq));
    }
}

// ---------------------------------------------------------------------------
extern "C" void kernel_launch(void* const* d_in, const int* in_sizes, int n_in,
                              void* d_out, int out_size, void* d_ws, size_t ws_size,
                              hipStream_t stream) {
    const float* x = (const float*)d_in[0];   // (256, 8, 1152)
    const float* W = (const float*)d_in[1];   // (1, 1152, 10, 16, 8)
    float* out = (float*)d_out;               // (256, 10, 16)

    float* part = (float*)d_ws;               // [256][18][160] fp32 = 2.95 MB

    dim3 gg(B_TOT / 16, SG, JG);
    gemm_direct<<<gg, 256, 0, stream>>>(x, W, part);

    reduce_squash<<<B_TOT, 192, 0, stream>>>(part, out);
}

// Round 6
// 18.057 us; speedup vs baseline: 10.8206x; 1.0338x over previous
//
#include <hip/hip_runtime.h>
#include <hip/hip_bf16.h>
#include <math.h>

// Problem constants
#define B_TOT 256
#define N_N   8
#define P_P   1152
#define J_J   160        // L*O
#define K_K   9216       // N_N * P_P
#define L_L   10

// Split-K: slice sg owns k-subset {n*1152 + p : p in [64*sg, 64*sg+64), all n}
// Block-local k order: kk = dp*8 + n  (dp = p - 64*sg)
#define SG 18
#define JG 5

typedef __attribute__((ext_vector_type(8))) short short8;   // 8 x bf16
typedef __attribute__((ext_vector_type(4))) float f32x4;

__device__ __forceinline__ short f2bf(float f) {
    __hip_bfloat16 h = __float2bfloat16(f);   // native v_cvt (RNE) on gfx950
    return __builtin_bit_cast(short, h);
}

// ---------------------------------------------------------------------------
// Kernel 1: split-K MFMA GEMM reading x and W directly.
// grid = (8 bt, 18 sg, 5 jg), 256 threads = 4 waves. No device-scope fences.
// Block tile: 32 b x 32 j x 512 k; wave w owns kk in [w*128, w*128+128).
// Stage: x-tile 32b x 512kk -> As bf16 (LDS transpose, rows padded to 520).
// B-frags straight from W: kk = dp*8+n -> p = p0+dp; row j: W[p*1280+j*8+n].
// Per wave: 4 ks x 4 MFMA (2 b-tiles x 2 j-tiles).
// Block LDS-reduces 4 waves -> one partial write part[b][sg][j].
// ---------------------------------------------------------------------------
__global__ __launch_bounds__(256) void gemm_direct(const float* __restrict__ x,
                                                   const float* __restrict__ W,
                                                   float* __restrict__ part) {
    const int bt = blockIdx.x;      // 0..7
    const int sg = blockIdx.y;      // 0..17
    const int jg = blockIdx.z;      // 0..4
    const int tid  = threadIdx.x;
    const int w    = tid >> 6;      // wave 0..3
    const int lane = tid & 63;
    const int b0 = bt * 32;
    const int p0 = sg * 64;
    const int j0 = jg * 32;

    __shared__ short As[32][520];        // [b][kk], rows padded (2-way alias only)
    __shared__ float redux[4][64][17];   // +1 pad breaks 16-way write conflict

    // ---- stage x-tile: lane = dp; 8 rows per wave, coalesced dword loads ----
    #pragma unroll
    for (int i = 0; i < 8; ++i) {
        const int bb = w * 8 + i;
        const float* xr = x + (size_t)(b0 + bb) * K_K + p0 + lane;
        short8 sh;
        #pragma unroll
        for (int n = 0; n < 8; ++n)
            sh[n] = f2bf(xr[(size_t)n * P_P]);
        *reinterpret_cast<short8*>(&As[bb][lane * 8]) = sh;  // kk = lane*8 + n
    }
    __syncthreads();

    const int m  = lane & 15;
    const int kq = lane >> 4;       // 0..3

    f32x4 acc00 = {0.f, 0.f, 0.f, 0.f};
    f32x4 acc01 = {0.f, 0.f, 0.f, 0.f};
    f32x4 acc10 = {0.f, 0.f, 0.f, 0.f};
    f32x4 acc11 = {0.f, 0.f, 0.f, 0.f};

    // B base: p = p0 + w*16 + ks*4 + kq, j = j0 + m (+16 for j-chain 1)
    const float* wbase = W + (size_t)(p0 + w * 16 + kq) * 1280 + (size_t)(j0 + m) * 8;

    #pragma unroll
    for (int ks = 0; ks < 4; ++ks) {
        const short8 af0 =
            *reinterpret_cast<const short8*>(&As[m][w * 128 + ks * 32 + kq * 8]);
        const short8 af1 =
            *reinterpret_cast<const short8*>(&As[m + 16][w * 128 + ks * 32 + kq * 8]);
        const float* wp0 = wbase + (size_t)ks * 4 * 1280;
        const float* wp1 = wp0 + 128;     // j += 16
        const f32x4 a0 = *reinterpret_cast<const f32x4*>(wp0);
        const f32x4 a1 = *reinterpret_cast<const f32x4*>(wp0 + 4);
        const f32x4 c0 = *reinterpret_cast<const f32x4*>(wp1);
        const f32x4 c1 = *reinterpret_cast<const f32x4*>(wp1 + 4);
        short8 bf0, bf1;
        bf0[0] = f2bf(a0.x); bf0[1] = f2bf(a0.y); bf0[2] = f2bf(a0.z); bf0[3] = f2bf(a0.w);
        bf0[4] = f2bf(a1.x); bf0[5] = f2bf(a1.y); bf0[6] = f2bf(a1.z); bf0[7] = f2bf(a1.w);
        bf1[0] = f2bf(c0.x); bf1[1] = f2bf(c0.y); bf1[2] = f2bf(c0.z); bf1[3] = f2bf(c0.w);
        bf1[4] = f2bf(c1.x); bf1[5] = f2bf(c1.y); bf1[6] = f2bf(c1.z); bf1[7] = f2bf(c1.w);
        acc00 = __builtin_amdgcn_mfma_f32_16x16x32_bf16(af0, bf0, acc00, 0, 0, 0);
        acc01 = __builtin_amdgcn_mfma_f32_16x16x32_bf16(af0, bf1, acc01, 0, 0, 0);
        acc10 = __builtin_amdgcn_mfma_f32_16x16x32_bf16(af1, bf0, acc10, 0, 0, 0);
        acc11 = __builtin_amdgcn_mfma_f32_16x16x32_bf16(af1, bf1, acc11, 0, 0, 0);
    }

    // ---- cross-wave split-K reduce in LDS (deterministic order) ----
    #pragma unroll
    for (int r = 0; r < 4; ++r) {
        redux[w][lane][r]      = acc00[r];
        redux[w][lane][r + 4]  = acc01[r];
        redux[w][lane][r + 8]  = acc10[r];
        redux[w][lane][r + 12] = acc11[r];
    }
    __syncthreads();

    // 1024 block outputs; each thread writes 4.
    #pragma unroll
    for (int f = tid; f < 1024; f += 256) {
        const int ln = f >> 4;
        const int c  = f & 15;
        const float s = redux[0][ln][c] + redux[1][ln][c]
                      + redux[2][ln][c] + redux[3][ln][c];
        const int mm = ln & 15;
        const int kk = ln >> 4;
        const int bi = c >> 3;          // b half (af0/af1)
        const int ji = (c >> 2) & 1;    // j half (bf0/bf1)
        const int r  = c & 3;
        const int b  = b0 + bi * 16 + kk * 4 + r;
        const int j  = j0 + ji * 16 + mm;
        part[((size_t)b * SG + sg) * J_J + j] = s;
    }
}

// ---------------------------------------------------------------------------
// Kernel 2: reduce partials over slices + squash (norm over L axis) -> out
// part[b][si][j]: per-b strip is SG*160 floats contiguous.
// ---------------------------------------------------------------------------
__global__ __launch_bounds__(192) void reduce_squash(const float* __restrict__ part,
                                                     float* __restrict__ out) {
    const int b = blockIdx.x;
    const int j = threadIdx.x;
    __shared__ float sld[J_J];
    float s = 0.0f;
    if (j < J_J) {
        const float* pb = part + (size_t)b * SG * J_J + j;
        #pragma unroll 6
        for (int si = 0; si < SG; ++si)
            s += pb[(size_t)si * J_J];
        sld[j] = s;
    }
    __syncthreads();
    if (j < J_J) {
        const int o = j & 15;
        float msq = 0.0f;
        #pragma unroll
        for (int l = 0; l < L_L; ++l) {
            const float v = sld[l * 16 + o];
            msq = fmaf(v, v, msq);
        }
        const float mag = sqrtf(msq);
        out[(size_t)b * J_J + j] = s * (mag / (1.0f + msq));
    }
}

// ---------------------------------------------------------------------------
extern "C" void kernel_launch(void* const* d_in, const int* in_sizes, int n_in,
                              void* d_out, int out_size, void* d_ws, size_t ws_size,
                              hipStream_t stream) {
    const float* x = (const float*)d_in[0];   // (256, 8, 1152)
    const float* W = (const float*)d_in[1];   // (1, 1152, 10, 16, 8)
    float* out = (float*)d_out;               // (256, 10, 16)

    float* part = (float*)d_ws;               // [256][18][160] fp32 = 2.95 MB

    dim3 gg(B_TOT / 32, SG, JG);
    gemm_direct<<<gg, 256, 0, stream>>>(x, W, part);

    reduce_squash<<<B_TOT, 192, 0, stream>>>(part, out);
}